// Round 2
// baseline (233.604 us; speedup 1.0000x reference)
//
#include <hip/hip_runtime.h>
#include <math.h>

#define NTOK   32768
#define DIM    512
#define NTYPES 26
#define PT     128
#define NCODES 3328
#define NSAMP  312
#define INV_TEMP (1.0f / 0.07f)
#define MAXTILES 24

typedef __attribute__((ext_vector_type(8))) short short8;
typedef __attribute__((ext_vector_type(4))) float floatx4;

// split f into bf16 hi + bf16 lo (RNE both), f ~= hi + lo to ~2^-17 rel
__device__ __forceinline__ void f2bf2(float f, unsigned short& h, unsigned short& l) {
    unsigned u = __float_as_uint(f);
    unsigned hb = (u + 0x7fffu + ((u >> 16) & 1u)) >> 16;
    h = (unsigned short)hb;
    float hf = __uint_as_float(hb << 16);
    float r = f - hf;
    unsigned u2 = __float_as_uint(r);
    l = (unsigned short)((u2 + 0x7fffu + ((u2 >> 16) & 1u)) >> 16);
}

// ---------------- emb precompute: bf16 hi/lo planes PRE-SWIZZLED into MFMA fragment
// order + sume + rinv; zero-init globals ----------------
// Fragment layout per type slab (65536 shorts): frag (ks2,ni) at (ks2*8+ni)*512,
// within frag lane l = q4*16+lc holds code (ni*16+lc), k = ks2*32+q4*8 .. +8.
// So k_main's B loads are lane-contiguous (fully coalesced dwordx4).
__global__ __launch_bounds__(256) void k_emb(const float* __restrict__ emb,
                                             unsigned short* __restrict__ Bhg,
                                             unsigned short* __restrict__ Blg,
                                             float* __restrict__ sume,
                                             float* __restrict__ rinv,
                                             int* __restrict__ counts,
                                             float* __restrict__ accg) {
    int tid = threadIdx.x;
    if (blockIdx.x == 0) {
        if (tid < NTYPES) counts[tid] = 0;
        if (tid == 32) accg[0] = 0.0f;
        if (tid == 33) accg[1] = 0.0f;
    }
    int wv = tid >> 6, lane = tid & 63;
    int c = blockIdx.x * 4 + wv;
    const float4* row = (const float4*)(emb + (size_t)c * DIM);
    float4 v0 = row[lane * 2], v1 = row[lane * 2 + 1];   // elems k = lane*8 .. +8
    float s = v0.x*v0.x + v0.y*v0.y + v0.z*v0.z + v0.w*v0.w
            + v1.x*v1.x + v1.y*v1.y + v1.z*v1.z + v1.w*v1.w;
    for (int m = 32; m; m >>= 1) s += __shfl_xor(s, m);
    if (lane == 0) {
        sume[c] = s;
        rinv[c] = 1.0f / fmaxf(sqrtf(s), 1e-12f);
    }
    union { short8 v; unsigned short u[8]; } hh, ll;
    f2bf2(v0.x, hh.u[0], ll.u[0]); f2bf2(v0.y, hh.u[1], ll.u[1]);
    f2bf2(v0.z, hh.u[2], ll.u[2]); f2bf2(v0.w, hh.u[3], ll.u[3]);
    f2bf2(v1.x, hh.u[4], ll.u[4]); f2bf2(v1.y, hh.u[5], ll.u[5]);
    f2bf2(v1.z, hh.u[6], ll.u[6]); f2bf2(v1.w, hh.u[7], ll.u[7]);
    // source: code c, k-chunk = lane*8  ->  ks2 = lane>>2, q4 = lane&3
    int qq  = c >> 7;
    int n   = c & 127;
    int ni  = n >> 4, lcc = n & 15;
    int ks2 = lane >> 2, q4d = lane & 3;
    size_t dst = (size_t)qq * (PT * DIM)
               + (size_t)(((ks2 * 8 + ni) * 64 + q4d * 16 + lcc) * 8);
    *(short8*)(Bhg + dst) = hh.v;
    *(short8*)(Blg + dst) = ll.v;
}

// ---------------- two-level histogram: rank within type ----------------
__global__ __launch_bounds__(256) void k_hist(const int* __restrict__ Q,
                                              int* __restrict__ counts,
                                              int* __restrict__ rank) {
    __shared__ int lbin[NTYPES];
    __shared__ int lbase[NTYPES];
    int tid = threadIdx.x;
    if (tid < NTYPES) lbin[tid] = 0;
    __syncthreads();
    int t = blockIdx.x * 256 + tid;
    int qt = Q[t];
    int lr = atomicAdd(&lbin[qt], 1);
    __syncthreads();
    if (tid < NTYPES) lbase[tid] = atomicAdd(&counts[tid], lbin[tid]);
    __syncthreads();
    rank[t] = lbase[qt] + lr;
}

// ---------------- scatter (with in-block scan); block 0 publishes offs ----------------
__global__ __launch_bounds__(256) void k_scatter(const int* __restrict__ Q,
                                                 const int* __restrict__ counts,
                                                 const int* __restrict__ rank,
                                                 int* __restrict__ order,
                                                 int* __restrict__ offsg) {
    __shared__ int offs[NTYPES];
    int tid = threadIdx.x;
    if (tid == 0) {
        int a = 0;
        for (int i = 0; i < NTYPES; i++) {
            offs[i] = a;
            if (blockIdx.x == 0) offsg[i] = a;
            a += counts[i];
        }
        if (blockIdx.x == 0) offsg[NTYPES] = a;
    }
    __syncthreads();
    int t = blockIdx.x * 256 + tid;
    order[offs[Q[t]] + rank[t]] = t;
}

// ---------------- main: barrier-free per-wave MFMA distance GEMM ----------------
// Each wave owns 16 tokens x all 128 codes of its type. Zero LDS, zero __syncthreads:
// A fragments come straight from gathered x rows (f32 -> bf16 hi/lo in-register),
// B fragments are coalesced loads from the pre-swizzled L2-resident slab.
// Latency hiding via TLP: 16 waves/CU free-running, no collective vmcnt(0) drains.
__global__ __launch_bounds__(256, 4) void k_main(const float* __restrict__ x,
                                                 const float* __restrict__ emb,
                                                 const unsigned short* __restrict__ Bhg,
                                                 const unsigned short* __restrict__ Blg,
                                                 const int* __restrict__ order,
                                                 const int* __restrict__ offsg,
                                                 const float* __restrict__ sume,
                                                 const float* __restrict__ rinv,
                                                 float* __restrict__ outbuf,
                                                 float* __restrict__ idxout,
                                                 float* __restrict__ accg) {
    int q = blockIdx.x;
    int base = offsg[q];
    int cnt = offsg[q + 1] - base;
    int wv = threadIdx.x >> 6;
    int tstart = blockIdx.y * 64 + wv * 16;        // this wave's token window
    if (tstart >= cnt) return;                      // wave-uniform exit; no barriers exist
    int ntw = min(16, cnt - tstart);

    int lane = threadIdx.x & 63;
    int lc = lane & 15, q4 = lane >> 4;

    // A row for this lane: token row lc (clamped tail duplicates row ntw-1)
    int tok = order[base + tstart + min(lc, ntw - 1)];
    const float* ap = x + (size_t)tok * DIM + q4 * 8;

    const unsigned short* bh = Bhg + (size_t)q * (PT * DIM) + lane * 8;
    const unsigned short* bl = Blg + (size_t)q * (PT * DIM) + lane * 8;

    float sv[8];
#pragma unroll
    for (int ni = 0; ni < 8; ni++) sv[ni] = sume[q * PT + ni * 16 + lc];

    floatx4 acc[8];
#pragma unroll
    for (int i = 0; i < 8; i++) acc[i] = (floatx4){0.f, 0.f, 0.f, 0.f};
    float ps = 0.0f;   // sumsq partial for row lc, k-slices q4*8 per ks2

    for (int ks2 = 0; ks2 < 16; ks2++) {
        float4 a0 = *(const float4*)(ap);
        float4 a1 = *(const float4*)(ap + 4);
        ap += 32;
        ps = fmaf(a0.x, a0.x, fmaf(a0.y, a0.y, fmaf(a0.z, a0.z, fmaf(a0.w, a0.w, ps))));
        ps = fmaf(a1.x, a1.x, fmaf(a1.y, a1.y, fmaf(a1.z, a1.z, fmaf(a1.w, a1.w, ps))));
        union { short8 v; unsigned short u[8]; } ah, al;
        f2bf2(a0.x, ah.u[0], al.u[0]); f2bf2(a0.y, ah.u[1], al.u[1]);
        f2bf2(a0.z, ah.u[2], al.u[2]); f2bf2(a0.w, ah.u[3], al.u[3]);
        f2bf2(a1.x, ah.u[4], al.u[4]); f2bf2(a1.y, ah.u[5], al.u[5]);
        f2bf2(a1.z, ah.u[6], al.u[6]); f2bf2(a1.w, ah.u[7], al.u[7]);

        const unsigned short* bkh = bh + ks2 * 4096;   // 8 frags * 512 shorts
        const unsigned short* bkl = bl + ks2 * 4096;
#pragma unroll
        for (int h = 0; h < 2; h++) {                  // halve live B regs -> occupancy
            short8 bhf[4], blf[4];
#pragma unroll
            for (int j = 0; j < 4; j++) {
                bhf[j] = *(const short8*)(bkh + (h * 4 + j) * 512);
                blf[j] = *(const short8*)(bkl + (h * 4 + j) * 512);
            }
#pragma unroll
            for (int j = 0; j < 4; j++) {
                acc[h * 4 + j] = __builtin_amdgcn_mfma_f32_16x16x32_bf16(ah.v, bhf[j], acc[h * 4 + j], 0, 0, 0);
                acc[h * 4 + j] = __builtin_amdgcn_mfma_f32_16x16x32_bf16(ah.v, blf[j], acc[h * 4 + j], 0, 0, 0);
                acc[h * 4 + j] = __builtin_amdgcn_mfma_f32_16x16x32_bf16(al.v, bhf[j], acc[h * 4 + j], 0, 0, 0);
            }
        }
    }

    // rnorm: sum the 4 q4-partials of each row; afterwards lane L holds rn of row L&15
    ps += __shfl_xor(ps, 16);
    ps += __shfl_xor(ps, 32);
    float rnv = 1.0f / fmaxf(sqrtf(ps), 1e-12f);

    // argmin over codes. C/D layout: col = lc = code%16, row = q4*4+reg = token
    float termsum = 0.0f;
    int bca[4];
#pragma unroll
    for (int r = 0; r < 4; r++) {
        int row = q4 * 4 + r;
        float rn2 = -2.0f * __shfl(rnv, row);
        float bv = 1e30f; int bc = 0;
#pragma unroll
        for (int ni = 0; ni < 8; ni++) {
            float d = fmaf(rn2, acc[ni][r], sv[ni]);
            int n = ni * 16 + lc;
            if (d < bv) { bv = d; bc = n; }            // ni ascending: strict < keeps lowest
        }
#pragma unroll
        for (int mk = 1; mk <= 8; mk <<= 1) {          // reduce across the 16-lane col group
            float ov = __shfl_xor(bv, mk);
            int oc = __shfl_xor(bc, mk);
            if (ov < bv || (ov == bv && oc < bc)) { bv = ov; bc = oc; }
        }
        bca[r] = bc;
        int gt = __shfl(tok, row);                     // hoisted out of divergent branch
        if (lc == 0 && row < ntw) {
            idxout[gt] = (float)(q * PT + bc);
            float se = sume[q * PT + bc];
            float rc = rinv[q * PT + bc];
            termsum += 2.0f - (se - bv) * rc;          // bv = sume_c - 2*rn*dot
        }
    }
    // termsum lives on lanes 0,16,32,48 -> sum and one atomic per wave
    termsum += __shfl_xor(termsum, 16);
    termsum += __shfl_xor(termsum, 32);
    if (lane == 0) atomicAdd(&accg[0], termsum);

    // epilogue: out = quantized = emb[c]*rinv_c (== xn + (q - xn) numerically)
#pragma unroll
    for (int g = 0; g < 4; g++) {
#pragma unroll
        for (int r = 0; r < 4; r++) {
            int row = g * 4 + r;                       // compile-time constant, wave-uniform guard
            if (row >= ntw) continue;
            int c = __shfl(bca[r], g * 16);
            int gt = __shfl(tok, row);
            float rv = rinv[q * PT + c];
            const float4* er = (const float4*)(emb + (size_t)(q * PT + c) * DIM);
            float4* orow = (float4*)(outbuf + (size_t)gt * DIM);
            float4 e0 = er[lane * 2], e1 = er[lane * 2 + 1];
            orow[lane * 2]     = make_float4(e0.x * rv, e0.y * rv, e0.z * rv, e0.w * rv);
            orow[lane * 2 + 1] = make_float4(e1.x * rv, e1.y * rv, e1.z * rv, e1.w * rv);
        }
    }
}

// ---------------- uniform loss: block per row i, wave-per-j, 4-j batched ----------------
__global__ __launch_bounds__(256) void k_uloss(const float* __restrict__ emb,
                                               const int* __restrict__ samp,
                                               const float* __restrict__ rinv,
                                               float* __restrict__ accg) {
    __shared__ float rs[4], rp[4];
    int i = blockIdx.x;
    int tid = threadIdx.x;
    int lane = tid & 63, wv = tid >> 6;
    int ci = samp[i];
    float rvi = rinv[ci];
    int labi = ci >> 7;
    const float4* ri = (const float4*)(emb + (size_t)ci * DIM);
    float4 e0 = ri[lane * 2], e1 = ri[lane * 2 + 1];
    float sE = 0.0f, pE = 0.0f;
    for (int j0 = wv; j0 < NSAMP; j0 += 16) {
        float d[4]; int cj[4]; bool val[4];
#pragma unroll
        for (int u = 0; u < 4; u++) {
            int j = j0 + u * 4;
            val[u] = (j < NSAMP) && (j != i);
            int js = val[u] ? j : 0;
            cj[u] = samp[js];
            const float4* rj = (const float4*)(emb + (size_t)cj[u] * DIM);
            float4 f0 = rj[lane * 2], f1 = rj[lane * 2 + 1];
            d[u] = e0.x*f0.x + e0.y*f0.y + e0.z*f0.z + e0.w*f0.w
                 + e1.x*f1.x + e1.y*f1.y + e1.z*f1.z + e1.w*f1.w;
        }
#pragma unroll
        for (int mk = 32; mk; mk >>= 1)
#pragma unroll
            for (int u = 0; u < 4; u++) d[u] += __shfl_xor(d[u], mk);
#pragma unroll
        for (int u = 0; u < 4; u++) {
            float ex = val[u] ? expf(d[u] * rvi * rinv[cj[u]] * INV_TEMP) : 0.0f;
            sE += ex;
            if (val[u] && (cj[u] >> 7) == labi) pE += ex;
        }
    }
    if (lane == 0) { rs[wv] = sE; rp[wv] = pE; }
    __syncthreads();
    if (tid == 0) {
        float S = rs[0] + rs[1] + rs[2] + rs[3];
        float P = rp[0] + rp[1] + rp[2] + rp[3];
        atomicAdd(&accg[1], logf(S) - logf(P));
    }
}

// ---------------- finalize scalars ----------------
__global__ void k_final(const float* __restrict__ accg, float* __restrict__ lossp) {
    // accg[0] = sum over tokens of ||q - xn||^2 (row sums); reference mean is over NTOK*DIM
    lossp[0] = (1.25f / ((float)NTOK * (float)DIM)) * accg[0];
    lossp[1] = accg[1] / (float)NSAMP;
}

extern "C" void kernel_launch(void* const* d_in, const int* in_sizes, int n_in,
                              void* d_out, int out_size, void* d_ws, size_t ws_size,
                              hipStream_t stream) {
    const float* x   = (const float*)d_in[0];
    const float* emb = (const float*)d_in[1];
    const int* Q     = (const int*)d_in[2];
    const int* samp  = (const int*)d_in[3];

    float* out    = (float*)d_out;                       // [NTOK*DIM]
    float* lossp  = out + (size_t)NTOK * DIM;            // loss, uloss
    float* idxout = out + (size_t)NTOK * DIM + 2;        // [NTOK] idx as float

    unsigned short* Bhg = (unsigned short*)d_ws;         // NCODES*DIM bf16-hi (frag-swizzled)
    unsigned short* Blg = Bhg + (size_t)NCODES * DIM;    // NCODES*DIM bf16-lo (frag-swizzled)
    float* sume  = (float*)(Blg + (size_t)NCODES * DIM); // NCODES
    float* rinv  = sume + NCODES;                        // NCODES
    int* counts  = (int*)(rinv + NCODES);                // NTYPES
    int* offsg   = counts + NTYPES;                      // NTYPES+1
    int* rank    = offsg + NTYPES + 1;                   // NTOK
    int* order   = rank + NTOK;                          // NTOK
    float* accg  = (float*)(order + NTOK);               // [2]

    k_emb<<<NCODES / 4, 256, 0, stream>>>(emb, Bhg, Blg, sume, rinv, counts, accg);
    k_hist<<<NTOK / 256, 256, 0, stream>>>(Q, counts, rank);
    k_scatter<<<NTOK / 256, 256, 0, stream>>>(Q, counts, rank, order, offsg);
    dim3 gmain(NTYPES, MAXTILES);
    k_main<<<gmain, 256, 0, stream>>>(x, emb, Bhg, Blg, order, offsg, sume, rinv, out, idxout, accg);
    k_uloss<<<NSAMP, 256, 0, stream>>>(emb, samp, rinv, accg);
    k_final<<<1, 1, 0, stream>>>(accg, lossp);
}